// Round 3
// baseline (10780.659 us; speedup 1.0000x reference)
//
#include <hip/hip_runtime.h>
#include <hip/hip_bf16.h>

#define NG 50
#define NB 128

__device__ __forceinline__ float sspf(float x){
  float t = __expf(-fabsf(x));
  return fmaxf(x, 0.f) + __logf(1.f + t) - 0.6931471805599453094f;
}

constexpr float RBF_STEP  = 5.0f / 49.0f;
constexpr float RBF_COEFF = -0.5f / (RBF_STEP * RBF_STEP);

// ---------------- h = embed[r] ----------------
__global__ void embed_k(const int* __restrict__ r, const float* __restrict__ embed,
                        float* __restrict__ h, int N){
  int idx = blockIdx.x * blockDim.x + threadIdx.x;
  if (idx < N * 32){
    int n = idx >> 5, c = (idx & 31) * 4;
    *(float4*)&h[(size_t)n * NB + c] = *(const float4*)&embed[(size_t)r[n] * NB + c];
  }
}

// ---------------- per-edge distance ----------------
__global__ void dist_k(const int* __restrict__ a, const float* __restrict__ xyz,
                       float* __restrict__ d, int E){
  int e = blockIdx.x * blockDim.x + threadIdx.x;
  if (e < E){
    int i = a[2*e], j = a[2*e+1];
    float dx = xyz[3*i+0] - xyz[3*j+0];
    float dy = xyz[3*i+1] - xyz[3*j+1];
    float dz = xyz[3*i+2] - xyz[3*j+2];
    d[e] = sqrtf(dx*dx + dy*dy + dz*dz);
  }
}

// ---------------- generic (N x 128) @ (128 x 128) + b, opt ssp, opt residual ----
// block: 128 threads, tile 64 rows x 128 cols, per-thread 8 rows x 8 cols.
template<int ACT, int RESID>
__launch_bounds__(128, 3)
__global__ void gemm128_k(const float* __restrict__ in, const float* __restrict__ W,
                          const float* __restrict__ bias, float* __restrict__ out, int N){
  __shared__ float As[32][64];    // transposed: As[k][row] — conflict-free b128 reads
  __shared__ float Ws[32][128];
  int tid = threadIdx.x;
  int tc = tid & 15, tr = tid >> 4;          // tr 0..7 (8 rows each), tc 0..15 (8 cols each)
  int row0 = blockIdx.x * 64;
  int c0 = tc * 8;

  float bcol[8];
  {
    float4 b0 = *(const float4*)&bias[c0];
    float4 b1 = *(const float4*)&bias[c0+4];
    bcol[0]=b0.x; bcol[1]=b0.y; bcol[2]=b0.z; bcol[3]=b0.w;
    bcol[4]=b1.x; bcol[5]=b1.y; bcol[6]=b1.z; bcol[7]=b1.w;
  }
  float acc[8][8];
  #pragma unroll
  for (int r=0;r<8;r++)
    #pragma unroll
    for (int q=0;q<8;q++) acc[r][q] = bcol[q];

  for (int kc=0; kc<4; kc++){
    // stage A chunk (64 rows x 32 k), transposed into LDS
    #pragma unroll
    for (int p=0;p<4;p++){
      int f = tid + 128*p;            // 0..511
      int rr = f >> 3, kq = f & 7;
      int grow = row0 + rr;
      float4 v = (grow < N) ? *(const float4*)&in[(size_t)grow*NB + kc*32 + kq*4]
                            : make_float4(0.f,0.f,0.f,0.f);
      As[kq*4+0][rr] = v.x; As[kq*4+1][rr] = v.y;
      As[kq*4+2][rr] = v.z; As[kq*4+3][rr] = v.w;
    }
    // stage W chunk (32 k x 128 cols)
    #pragma unroll
    for (int p=0;p<8;p++){
      int f = tid + 128*p;            // 0..1023
      int wk = f >> 5, cq = f & 31;
      *(float4*)&Ws[wk][cq*4] = *(const float4*)&W[(size_t)(kc*32+wk)*NB + cq*4];
    }
    __syncthreads();
    #pragma unroll 4
    for (int k=0;k<32;k++){
      float4 a0 = *(const float4*)&As[k][tr*8];
      float4 a1 = *(const float4*)&As[k][tr*8+4];
      float4 w0 = *(const float4*)&Ws[k][c0];
      float4 w1 = *(const float4*)&Ws[k][c0+4];
      float av[8] = {a0.x,a0.y,a0.z,a0.w,a1.x,a1.y,a1.z,a1.w};
      float wv[8] = {w0.x,w0.y,w0.z,w0.w,w1.x,w1.y,w1.z,w1.w};
      #pragma unroll
      for (int r=0;r<8;r++)
        #pragma unroll
        for (int q=0;q<8;q++) acc[r][q] += av[r]*wv[q];
    }
    __syncthreads();
  }
  // epilogue
  #pragma unroll
  for (int r=0;r<8;r++){
    int row = row0 + tr*8 + r;
    if (row < N){
      float v[8];
      #pragma unroll
      for (int q=0;q<8;q++) v[q] = (ACT==1) ? sspf(acc[r][q]) : acc[r][q];
      if (RESID){
        float4 o0 = *(const float4*)&out[(size_t)row*NB + c0];
        float4 o1 = *(const float4*)&out[(size_t)row*NB + c0+4];
        v[0]+=o0.x; v[1]+=o0.y; v[2]+=o0.z; v[3]+=o0.w;
        v[4]+=o1.x; v[5]+=o1.y; v[6]+=o1.z; v[7]+=o1.w;
      }
      *(float4*)&out[(size_t)row*NB + c0]   = make_float4(v[0],v[1],v[2],v[3]);
      *(float4*)&out[(size_t)row*NB + c0+4] = make_float4(v[4],v[5],v[6],v[7]);
    }
  }
}

// ---------------- edge kernel: ef = ssp(g@We1+be1)@We2+be2, atomic scatter ----
// block 256 thr, 128 edges/tile. LDS buf[k][edge] holds g then T (transposed).
__launch_bounds__(256, 2)
__global__ void edge_k(const float* __restrict__ dists, const int* __restrict__ a,
                       const float* __restrict__ nodef,
                       const float* __restrict__ We1, const float* __restrict__ be1,
                       const float* __restrict__ We2, const float* __restrict__ be2,
                       float* __restrict__ agg, int E){
  __shared__ float We1s[NG][64];
  __shared__ float We2s[NG][NB];
  __shared__ float buf[NG][NB];     // [gauss_or_filter][edge]
  __shared__ float be1s[64], be2s[NB];
  __shared__ float ds_[NB];
  __shared__ int   ijs[2*NB];
  int tid = threadIdx.x;

  for (int idx = tid; idx < NG*64; idx += 256){
    int m = idx >> 6, k = idx & 63;
    We1s[m][k] = (k < NG) ? We1[m*NG + k] : 0.f;
  }
  for (int idx = tid; idx < NG*NB; idx += 256)
    We2s[0][idx] = We2[idx];
  if (tid < 64)  be1s[tid] = (tid < NG) ? be1[tid] : 0.f;
  if (tid < NB)  be2s[tid] = be2[tid];

  int ebase = blockIdx.x * NB;
  if (tid < NB){
    int e = ebase + tid;
    if (e < E){ ds_[tid] = dists[e]; ijs[2*tid] = a[2*e]; ijs[2*tid+1] = a[2*e+1]; }
    else      { ds_[tid] = 0.f;      ijs[2*tid] = -1;     ijs[2*tid+1] = -1; }
  }
  __syncthreads();

  // g phase: buf[m][e] = exp(coeff*(d_e - m*step)^2)
  for (int idx = tid; idx < NG*NB; idx += 256){
    int m = idx >> 7, e = idx & 127;
    float t = ds_[e] - RBF_STEP * (float)m;
    buf[m][e] = __expf(RBF_COEFF * t * t);
  }
  __syncthreads();

  int te = tid >> 4, tk = tid & 15;        // te: 8-edge group, tk: 4-k group / 8-chan group
  int e0 = te * 8, k0 = tk * 4;

  // T phase: T[k][e] = ssp(sum_m g[m][e]*We1[m][k] + be1[k])
  float tacc[8][4];
  {
    float4 bv = *(const float4*)&be1s[k0];
    float bq[4] = {bv.x,bv.y,bv.z,bv.w};
    #pragma unroll
    for (int r=0;r<8;r++)
      #pragma unroll
      for (int q=0;q<4;q++) tacc[r][q] = bq[q];
  }
  #pragma unroll 2
  for (int m=0;m<NG;m++){
    float4 w  = *(const float4*)&We1s[m][k0];
    float4 g0 = *(const float4*)&buf[m][e0];
    float4 g1 = *(const float4*)&buf[m][e0+4];
    float ge[8] = {g0.x,g0.y,g0.z,g0.w,g1.x,g1.y,g1.z,g1.w};
    float wv[4] = {w.x,w.y,w.z,w.w};
    #pragma unroll
    for (int r=0;r<8;r++)
      #pragma unroll
      for (int q=0;q<4;q++) tacc[r][q] += ge[r]*wv[q];
  }
  __syncthreads();   // all g reads complete before overwrite
  #pragma unroll
  for (int q=0;q<4;q++){
    int k = k0 + q;
    if (k < NG){
      float v[8];
      #pragma unroll
      for (int r=0;r<8;r++) v[r] = sspf(tacc[r][q]);
      *(float4*)&buf[k][e0]   = make_float4(v[0],v[1],v[2],v[3]);
      *(float4*)&buf[k][e0+4] = make_float4(v[4],v[5],v[6],v[7]);
    }
  }
  __syncthreads();

  // EF phase: ef[e][c] = sum_k T[k][e]*We2[k][c] + be2[c]; per-thread 8 edges x 8 chans
  int c0 = tk * 8;
  float acc[8][8];
  {
    float4 b0 = *(const float4*)&be2s[c0];
    float4 b1 = *(const float4*)&be2s[c0+4];
    float bq[8] = {b0.x,b0.y,b0.z,b0.w,b1.x,b1.y,b1.z,b1.w};
    #pragma unroll
    for (int r=0;r<8;r++)
      #pragma unroll
      for (int q=0;q<8;q++) acc[r][q] = bq[q];
  }
  #pragma unroll 2
  for (int k=0;k<NG;k++){
    float4 w0 = *(const float4*)&We2s[k][c0];
    float4 w1 = *(const float4*)&We2s[k][c0+4];
    float4 t0 = *(const float4*)&buf[k][e0];
    float4 t1 = *(const float4*)&buf[k][e0+4];
    float tv[8] = {t0.x,t0.y,t0.z,t0.w,t1.x,t1.y,t1.z,t1.w};
    float wv[8] = {w0.x,w0.y,w0.z,w0.w,w1.x,w1.y,w1.z,w1.w};
    #pragma unroll
    for (int r=0;r<8;r++)
      #pragma unroll
      for (int q=0;q<8;q++) acc[r][q] += tv[r]*wv[q];
  }

  // scatter: agg[i] += nodef[j]*ef ; agg[j] += nodef[i]*ef
  #pragma unroll
  for (int r=0;r<8;r++){
    int el = e0 + r;
    int i = ijs[2*el], j = ijs[2*el+1];
    if (i < 0) continue;
    float4 nj0 = *(const float4*)&nodef[(size_t)j*NB + c0];
    float4 nj1 = *(const float4*)&nodef[(size_t)j*NB + c0+4];
    float4 ni0 = *(const float4*)&nodef[(size_t)i*NB + c0];
    float4 ni1 = *(const float4*)&nodef[(size_t)i*NB + c0+4];
    float* ai = &agg[(size_t)i*NB + c0];
    float* aj = &agg[(size_t)j*NB + c0];
    float njv[8] = {nj0.x,nj0.y,nj0.z,nj0.w,nj1.x,nj1.y,nj1.z,nj1.w};
    float niv[8] = {ni0.x,ni0.y,ni0.z,ni0.w,ni1.x,ni1.y,ni1.z,ni1.w};
    #pragma unroll
    for (int q=0;q<8;q++){
      atomicAdd(ai+q, njv[q]*acc[r][q]);
      atomicAdd(aj+q, niv[q]*acc[r][q]);
    }
  }
}

// ---------------- readout: e = ssp(h@W1+b1)@W2+b2, molecule segment sum ------
__launch_bounds__(128, 3)
__global__ void readout_k(const float* __restrict__ h, const float* __restrict__ W1,
                          const float* __restrict__ b1, const float* __restrict__ W2,
                          const float* __restrict__ b2, const int* __restrict__ molp,
                          float* __restrict__ out, int N){
  __shared__ float As[32][64];
  __shared__ float W1s[32][64];
  __shared__ float segsum[2];
  int tid = threadIdx.x;
  int tc = tid & 15, tr = tid >> 4;         // tr 0..7 (8 rows), tc 0..15 (4 cols)
  int row0 = blockIdx.x * 64;
  int c0 = tc * 4;

  float acc[8][4];
  {
    float4 bv = *(const float4*)&b1[c0];
    float bq[4] = {bv.x,bv.y,bv.z,bv.w};
    #pragma unroll
    for (int r=0;r<8;r++)
      #pragma unroll
      for (int q=0;q<4;q++) acc[r][q] = bq[q];
  }
  for (int kc=0;kc<4;kc++){
    #pragma unroll
    for (int p=0;p<4;p++){
      int f = tid + 128*p; int rr = f >> 3; int kq = f & 7;
      int grow = row0 + rr;
      float4 v = (grow < N) ? *(const float4*)&h[(size_t)grow*NB + kc*32 + kq*4]
                            : make_float4(0.f,0.f,0.f,0.f);
      As[kq*4+0][rr] = v.x; As[kq*4+1][rr] = v.y;
      As[kq*4+2][rr] = v.z; As[kq*4+3][rr] = v.w;
    }
    #pragma unroll
    for (int p=0;p<4;p++){
      int f = tid + 128*p; int wk = f >> 4; int cq = f & 15;
      *(float4*)&W1s[wk][cq*4] = *(const float4*)&W1[(size_t)(kc*32+wk)*64 + cq*4];
    }
    __syncthreads();
    #pragma unroll 4
    for (int k=0;k<32;k++){
      float4 a0 = *(const float4*)&As[k][tr*8];
      float4 a1 = *(const float4*)&As[k][tr*8+4];
      float4 w  = *(const float4*)&W1s[k][c0];
      float av[8] = {a0.x,a0.y,a0.z,a0.w,a1.x,a1.y,a1.z,a1.w};
      float wv[4] = {w.x,w.y,w.z,w.w};
      #pragma unroll
      for (int r=0;r<8;r++)
        #pragma unroll
        for (int q=0;q<4;q++) acc[r][q] += av[r]*wv[q];
    }
    __syncthreads();
  }
  // ssp + dot with W2, reduce over tc group (16 lanes)
  float4 w2f = *(const float4*)&W2[c0];
  float part[8];
  #pragma unroll
  for (int r=0;r<8;r++)
    part[r] = sspf(acc[r][0])*w2f.x + sspf(acc[r][1])*w2f.y +
              sspf(acc[r][2])*w2f.z + sspf(acc[r][3])*w2f.w;
  #pragma unroll
  for (int off=1; off<16; off<<=1)
    #pragma unroll
    for (int r=0;r<8;r++) part[r] += __shfl_xor(part[r], off);

  if (tid < 2) segsum[tid] = 0.f;
  __syncthreads();
  int ms = molp[0];
  float b2v = b2[0];
  int seg0 = row0 / ms;
  if (tc == 0){
    #pragma unroll
    for (int r=0;r<8;r++){
      int row = row0 + tr*8 + r;
      if (row < N){
        int s = row/ms - seg0;
        if (s < 2) atomicAdd(&segsum[s], part[r] + b2v);
        else       atomicAdd(&out[row/ms], part[r] + b2v);
      }
    }
  }
  __syncthreads();
  if (tid == 0 && segsum[0] != 0.f) atomicAdd(&out[seg0], segsum[0]);
  if (tid == 1){
    int lastrow = row0 + 63; if (lastrow > N-1) lastrow = N-1;
    if (lastrow/ms > seg0 && segsum[1] != 0.f) atomicAdd(&out[seg0+1], segsum[1]);
  }
}

extern "C" void kernel_launch(void* const* d_in, const int* in_sizes, int n_in,
                              void* d_out, int out_size, void* d_ws, size_t ws_size,
                              hipStream_t stream){
  const int*   r     = (const int*)  d_in[0];
  const float* xyz   = (const float*)d_in[1];
  const int*   a     = (const int*)  d_in[2];
  const int*   molp  = (const int*)  d_in[3];
  const float* embed = (const float*)d_in[4];
  const float* Wn    = (const float*)d_in[5];
  const float* bn    = (const float*)d_in[6];
  const float* We1   = (const float*)d_in[7];
  const float* be1   = (const float*)d_in[8];
  const float* We2   = (const float*)d_in[9];
  const float* be2   = (const float*)d_in[10];
  const float* Wu1   = (const float*)d_in[11];
  const float* bu1   = (const float*)d_in[12];
  const float* Wu2   = (const float*)d_in[13];
  const float* bu2   = (const float*)d_in[14];
  const float* W1    = (const float*)d_in[15];
  const float* b1    = (const float*)d_in[16];
  const float* W2    = (const float*)d_in[17];
  const float* b2    = (const float*)d_in[18];

  int N = in_sizes[0];          // 50000
  int E = in_sizes[2] / 2;      // 500000

  float* ws   = (float*)d_ws;
  size_t E4   = ((size_t)E + 3) & ~(size_t)3;
  float* dbuf = ws;
  float* h    = dbuf + E4;
  float* nodef= h + (size_t)N*NB;     // also reused as u
  float* agg  = nodef + (size_t)N*NB;

  embed_k<<<(N*32 + 255)/256, 256, 0, stream>>>(r, embed, h, N);
  dist_k <<<(E + 255)/256,    256, 0, stream>>>(a, xyz, dbuf, E);

  int gblocks = (N + 63)/64;
  int eblocks = (E + 127)/128;
  for (int l = 0; l < 3; l++){
    gemm128_k<0,0><<<gblocks, 128, 0, stream>>>(h, Wn + (size_t)l*NB*NB, bn + l*NB, nodef, N);
    hipMemsetAsync(agg, 0, (size_t)N*NB*sizeof(float), stream);
    edge_k<<<eblocks, 256, 0, stream>>>(dbuf, a, nodef,
                                        We1 + (size_t)l*NG*NG, be1 + l*NG,
                                        We2 + (size_t)l*NG*NB, be2 + l*NB, agg, E);
    gemm128_k<1,0><<<gblocks, 128, 0, stream>>>(agg,   Wu1 + (size_t)l*NB*NB, bu1 + l*NB, nodef, N);
    gemm128_k<0,1><<<gblocks, 128, 0, stream>>>(nodef, Wu2 + (size_t)l*NB*NB, bu2 + l*NB, h, N);
  }
  hipMemsetAsync(d_out, 0, (size_t)out_size*sizeof(float), stream);
  readout_k<<<gblocks, 128, 0, stream>>>(h, W1, b1, W2, b2, molp, (float*)d_out, N);
}